// Round 4
// baseline (67773.230 us; speedup 1.0000x reference)
//
#include <hip/hip_runtime.h>

#define NB 8
#define NS 2048
#define ND 1024
#define NH 1024
#define NWG 128
#define TPB 512
#define HPW 8    /* h-coords per workgroup: NH / NWG */

#define SCOPE_AGENT __HIP_MEMORY_SCOPE_AGENT

__device__ __forceinline__ float sigmf(float v)     { return 1.f / (1.f + __expf(-v)); }
__device__ __forceinline__ float tanh_fast(float v) { return 1.f - 2.f / (1.f + __expf(2.f * v)); }

#define DOT4(acc, W, V)                 \
    acc = fmaf((W).x, (V).x, acc);      \
    acc = fmaf((W).y, (V).y, acc);      \
    acc = fmaf((W).z, (V).z, acc);      \
    acc = fmaf((W).w, (V).w, acc);

// 4 coherent (L2-bypassing) 16B loads, pipelined, one wait.
__device__ __forceinline__ void ld4_coherent(const float4* p0, const float4* p1,
                                             const float4* p2, const float4* p3,
                                             float4& a, float4& b, float4& c, float4& d) {
    asm volatile(
        "global_load_dwordx4 %0, %4, off sc0 sc1\n\t"
        "global_load_dwordx4 %1, %5, off sc0 sc1\n\t"
        "global_load_dwordx4 %2, %6, off sc0 sc1\n\t"
        "global_load_dwordx4 %3, %7, off sc0 sc1\n\t"
        "s_waitcnt vmcnt(0)"
        : "=&v"(a), "=&v"(b), "=&v"(c), "=&v"(d)
        : "v"(p0), "v"(p1), "v"(p2), "v"(p3)
        : "memory");
}

__global__ __launch_bounds__(TPB, 1)
void scan_kernel(const float* __restrict__ x,
                 const float* __restrict__ w_ih,
                 const float* __restrict__ w_hh,
                 const float* __restrict__ b_ih,
                 const float* __restrict__ b_hh,
                 const float* __restrict__ thrp,
                 float* __restrict__ membuf,              // 2 * NB*NH floats (double buffer)
                 unsigned long long* __restrict__ bitmap, // NB*NS*(NH/64) words
                 unsigned* __restrict__ bar,              // monotonic: 8 grp ctrs, super, flag
                 float* __restrict__ out_syn,
                 float* __restrict__ out_mem)
{
    __shared__ float x_s2[2][NB * NH];   // 64 KB double buffer for x_t
    __shared__ float m_s[NB * NH];       // 32 KB
    __shared__ float sg[4 * HPW * NB];   // gate pre-activations (1 KB)
    __shared__ float c_s[HPW * NB];      // cell state slice

    const int tid  = threadIdx.x;
    const int wg   = blockIdx.x;
    const int hb   = wg * HPW;
    const int wave = tid >> 6;          // 0..7
    const int lane = tid & 63;
    const int g    = wave & 3;          // gate (i,f,g,o)
    const int hh0  = (wave >> 2) * 4;   // h-subblock within WG: 0 or 4
    const int grp  = wg >> 4;           // 8 groups x 16 WGs
    const float thr = *thrp;

    if (tid < HPW * NB) c_s[tid] = 0.f;

    // ---- register-stationary weights: wave owns gate g, rows hb+hh0+rl (rl=0..3)
    float4 wih[4][4], whh[4][4];
    float bias[4];
    #pragma unroll
    for (int rl = 0; rl < 4; ++rl) {
        const int R = g * NH + hb + hh0 + rl;
        #pragma unroll
        for (int j = 0; j < 4; ++j) {
            wih[rl][j] = *(const float4*)(w_ih + (size_t)R * ND + j * 256 + lane * 4);
            whh[rl][j] = *(const float4*)(w_hh + (size_t)R * NH + j * 256 + lane * 4);
        }
        bias[rl] = b_ih[R] + b_hh[R];
    }

    float xacc[4][NB];   // per-lane PARTIAL x-dots for current step

    // ---- prologue: prefetch x(0), compute xacc(0)
    {
        #pragma unroll
        for (int j = 0; j < 4; ++j) {
            const int q = wave * 4 + j;               // chunk 0..31 (256 floats)
            const int b = q >> 2, d = (q & 3) * 256 + lane * 4;
            __builtin_amdgcn_global_load_lds(
                (const __attribute__((address_space(1))) unsigned int*)(x + ((size_t)b * NS + 0) * ND + d),
                (__attribute__((address_space(3))) unsigned int*)&x_s2[0][q * 256],
                16, 0, 0);
        }
        __syncthreads();
        #pragma unroll
        for (int b = 0; b < NB; ++b) {
            float4 xv[4];
            #pragma unroll
            for (int j = 0; j < 4; ++j)
                xv[j] = *(const float4*)(&x_s2[0][b * NH + j * 256 + lane * 4]);
            float a0 = 0.f, a1 = 0.f, a2 = 0.f, a3 = 0.f;
            #pragma unroll
            for (int j = 0; j < 4; ++j) {
                DOT4(a0, wih[0][j], xv[j]);
                DOT4(a1, wih[1][j], xv[j]);
                DOT4(a2, wih[2][j], xv[j]);
                DOT4(a3, wih[3][j], xv[j]);
            }
            xacc[0][b] = a0; xacc[1][b] = a1; xacc[2][b] = a2; xacc[3][b] = a3;
        }
    }

    for (int t = 0; t < NS; ++t) {
        const int cur = t & 1, nxt = (t + 1) & 1;
        const float* mcur = membuf + (size_t)cur * (NB * NH);
        float*       mnxt = membuf + (size_t)nxt * (NB * NH);

        // ---- issue prefetch of x(t+1) (fire-and-forget; drains at next syncthreads)
        if (t < NS - 1) {
            #pragma unroll
            for (int j = 0; j < 4; ++j) {
                const int q = wave * 4 + j;
                const int b = q >> 2, d = (q & 3) * 256 + lane * 4;
                __builtin_amdgcn_global_load_lds(
                    (const __attribute__((address_space(1))) unsigned int*)(x + ((size_t)b * NS + (t + 1)) * ND + d),
                    (__attribute__((address_space(3))) unsigned int*)&x_s2[nxt][q * 256],
                    16, 0, 0);
            }
        }

        // ---- stage mem(t): 4 coherent dwordx4 per thread -> LDS
        {
            const float4* mb = (const float4*)mcur;
            float4 v0, v1, v2, v3;
            ld4_coherent(mb + tid, mb + tid + 512, mb + tid + 1024, mb + tid + 1536,
                         v0, v1, v2, v3);
            float4* ms4 = (float4*)m_s;
            ms4[tid]        = v0;
            ms4[tid + 512]  = v1;
            ms4[tid + 1024] = v2;
            ms4[tid + 1536] = v3;
        }
        __syncthreads();

        // ---- mem-part dots, merged with xacc partials, reduce
        #pragma unroll
        for (int b = 0; b < NB; ++b) {
            float4 mv[4];
            #pragma unroll
            for (int j = 0; j < 4; ++j)
                mv[j] = *(const float4*)(m_s + b * NH + j * 256 + lane * 4);
            float a0 = xacc[0][b], a1 = xacc[1][b], a2 = xacc[2][b], a3 = xacc[3][b];
            #pragma unroll
            for (int j = 0; j < 4; ++j) {
                DOT4(a0, whh[0][j], mv[j]);
                DOT4(a1, whh[1][j], mv[j]);
                DOT4(a2, whh[2][j], mv[j]);
                DOT4(a3, whh[3][j], mv[j]);
            }
            #pragma unroll
            for (int off = 32; off >= 1; off >>= 1) {
                a0 += __shfl_xor(a0, off);
                a1 += __shfl_xor(a1, off);
                a2 += __shfl_xor(a2, off);
                a3 += __shfl_xor(a3, off);
            }
            if (lane == 0) {
                sg[(g * HPW + hh0 + 0) * NB + b] = a0 + bias[0];
                sg[(g * HPW + hh0 + 1) * NB + b] = a1 + bias[1];
                sg[(g * HPW + hh0 + 2) * NB + b] = a2 + bias[2];
                sg[(g * HPW + hh0 + 3) * NB + b] = a3 + bias[3];
            }
        }
        __syncthreads();

        // ---- pointwise LSTM update: 64 threads (all in wave 0 -> vmcnt ordering works)
        if (tid < HPW * NB) {
            const int b = tid >> 3, hl = tid & 7;
            const int h = hb + hl;
            float gi_v = sg[(0 * HPW + hl) * NB + b];
            float gf_v = sg[(1 * HPW + hl) * NB + b];
            float gg_v = sg[(2 * HPW + hl) * NB + b];
            float go_v = sg[(3 * HPW + hl) * NB + b];
            float c  = c_s[tid];
            float cn = sigmf(gf_v) * c + sigmf(gi_v) * tanh_fast(gg_v);
            float hv = sigmf(go_v) * tanh_fast(cn);
            float mprev = m_s[b * NH + h];
            float reset = (mprev - thr > 0.f) ? 1.f : 0.f;   // snntorch: reset from PREV mem
            float mn = hv - reset * thr;
            c_s[tid] = cn;
            __hip_atomic_store((unsigned*)(mnxt + b * NH + h), __float_as_uint(mn),
                               __ATOMIC_RELAXED, SCOPE_AGENT);
            if (mn - thr > 0.f)
                atomicOr(bitmap + (size_t)(b * NS + t) * (NH / 64) + (h >> 6),
                         1ull << (h & 63));
            if (t == NS - 1) {
                out_syn[b * NH + h] = cn;
                out_mem[b * NH + h] = mn;
            }
        }

        if (t < NS - 1) {
            // ---- arrive: wave 0's release-RMW drains its own mem stores (vmcnt)
            if (tid == 0) {
                unsigned prev = __hip_atomic_fetch_add(bar + (grp << 4), 1u,
                                                       __ATOMIC_ACQ_REL, SCOPE_AGENT);
                if ((prev & 15u) == 15u) {
                    unsigned p2 = __hip_atomic_fetch_add(bar + 256, 1u,
                                                         __ATOMIC_ACQ_REL, SCOPE_AGENT);
                    if ((p2 & 7u) == 7u)
                        __hip_atomic_store(bar + 320, (unsigned)(t + 1),
                                           __ATOMIC_RELEASE, SCOPE_AGENT);
                }
            }

            // ---- x-part dots for t+1 (overlaps barrier wait)
            #pragma unroll
            for (int b = 0; b < NB; ++b) {
                float4 xv[4];
                #pragma unroll
                for (int j = 0; j < 4; ++j)
                    xv[j] = *(const float4*)(&x_s2[nxt][b * NH + j * 256 + lane * 4]);
                float a0 = 0.f, a1 = 0.f, a2 = 0.f, a3 = 0.f;
                #pragma unroll
                for (int j = 0; j < 4; ++j) {
                    DOT4(a0, wih[0][j], xv[j]);
                    DOT4(a1, wih[1][j], xv[j]);
                    DOT4(a2, wih[2][j], xv[j]);
                    DOT4(a3, wih[3][j], xv[j]);
                }
                xacc[0][b] = a0; xacc[1][b] = a1; xacc[2][b] = a2; xacc[3][b] = a3;
            }

            // ---- poll single release flag
            if (tid == 0) {
                const unsigned want = (unsigned)(t + 1);
                while (__hip_atomic_load(bar + 320, __ATOMIC_RELAXED, SCOPE_AGENT) < want)
                    __builtin_amdgcn_s_sleep(1);
            }
            asm volatile("" ::: "memory");
            __syncthreads();
        }
    }
}

// out[b,s,:] = dyt_w * tanh(alpha * (x + b_fc + spk @ w_fc^T)) + dyt_b
__global__ __launch_bounds__(256)
void out_kernel(const float* __restrict__ x,
                const float* __restrict__ b_fc,
                const float* __restrict__ w_fc,
                const float* __restrict__ alphap,
                const float* __restrict__ dytw,
                const float* __restrict__ dytb,
                const unsigned long long* __restrict__ bitmap,
                float* __restrict__ out)
{
    __shared__ unsigned long long wds[16];
    __shared__ int flag;
    const int row = blockIdx.x;      // b*NS + s
    const int tid = threadIdx.x;
    if (tid < 16) wds[tid] = bitmap[(size_t)row * 16 + tid];
    __syncthreads();
    if (tid == 0) {
        unsigned long long o = 0ull;
        #pragma unroll
        for (int i = 0; i < 16; ++i) o |= wds[i];
        flag = (o != 0ull);
    }
    __syncthreads();

    const float alpha = *alphap;
    const float* xr = x + (size_t)row * NH;
    float* orow = out + (size_t)row * NH;
    const int j0 = tid * 4;

    float4 xv = *(const float4*)(xr + j0);
    float4 bf = *(const float4*)(b_fc + j0);
    float4 dw = *(const float4*)(dytw + j0);
    float4 db = *(const float4*)(dytb + j0);
    float p[4]   = {xv.x, xv.y, xv.z, xv.w};
    float bfa[4] = {bf.x, bf.y, bf.z, bf.w};
    float dwa[4] = {dw.x, dw.y, dw.z, dw.w};
    float dba[4] = {db.x, db.y, db.z, db.w};

    #pragma unroll
    for (int u = 0; u < 4; ++u) {
        float v = p[u] + bfa[u];
        if (flag) {   // general spike path (cold on this data)
            const int j = j0 + u;
            for (int wi = 0; wi < 16; ++wi) {
                unsigned long long m = wds[wi];
                while (m) {
                    int bit = __ffsll(m) - 1;
                    m &= m - 1;
                    v += w_fc[(size_t)j * NH + wi * 64 + bit];
                }
            }
        }
        p[u] = dwa[u] * tanh_fast(alpha * v) + dba[u];
    }
    *(float4*)(orow + j0) = make_float4(p[0], p[1], p[2], p[3]);
}

extern "C" void kernel_launch(void* const* d_in, const int* in_sizes, int n_in,
                              void* d_out, int out_size, void* d_ws, size_t ws_size,
                              hipStream_t stream) {
    const float* x     = (const float*)d_in[0];
    const float* w_ih  = (const float*)d_in[1];
    const float* w_hh  = (const float*)d_in[2];
    const float* b_ih  = (const float*)d_in[3];
    const float* b_hh  = (const float*)d_in[4];
    const float* w_fc  = (const float*)d_in[5];
    const float* b_fc  = (const float*)d_in[6];
    const float* thr   = (const float*)d_in[7];
    const float* alpha = (const float*)d_in[8];
    const float* dytw  = (const float*)d_in[9];
    const float* dytb  = (const float*)d_in[10];

    float* out  = (float*)d_out;
    float* syn  = out + (size_t)NB * NS * NH;
    float* memf = syn + (size_t)NB * NH;

    char* ws = (char*)d_ws;
    unsigned* bar   = (unsigned*)ws;                                  // 4 KB barrier region
    float* membuf   = (float*)(ws + 4096);                            // 64 KB double buffer
    unsigned long long* bitmap = (unsigned long long*)(ws + 4096 + 2 * NB * NH * 4);

    size_t zbytes = 4096 + (size_t)2 * NB * NH * 4
                  + (size_t)NB * NS * (NH / 64) * 8;                  // ~2.17 MB
    (void)hipMemsetAsync(d_ws, 0, zbytes, stream);

    hipLaunchKernelGGL(scan_kernel, dim3(NWG), dim3(TPB), 0, stream,
                       x, w_ih, w_hh, b_ih, b_hh, thr, membuf, bitmap, bar, syn, memf);
    hipLaunchKernelGGL(out_kernel, dim3(NB * NS), dim3(256), 0, stream,
                       x, b_fc, w_fc, alpha, dytw, dytb, bitmap, out);
}

// Round 5
// 22649.240 us; speedup vs baseline: 2.9923x; 2.9923x over previous
//
#include <hip/hip_runtime.h>

#define NB 8
#define NS 2048
#define ND 1024
#define NH 1024
#define NWG 256
#define TPB 512
#define HPW 4        /* h-coords per WG = NH / NWG */
#define PSTRIDE 20   /* padded stride (in floats) for 16 partials, kills bank conflicts */

#define SCOPE_AGENT __HIP_MEMORY_SCOPE_AGENT

__device__ __forceinline__ float sigmf(float v)     { return 1.f / (1.f + __expf(-v)); }
__device__ __forceinline__ float tanh_fast(float v) { return 1.f - 2.f / (1.f + __expf(2.f * v)); }

#define DOT4(acc, W, V)                 \
    acc = fmaf((W).x, (V).x, acc);      \
    acc = fmaf((W).y, (V).y, acc);      \
    acc = fmaf((W).z, (V).z, acc);      \
    acc = fmaf((W).w, (V).w, acc);

__global__ __launch_bounds__(TPB, 2)
void scan_kernel(const float* __restrict__ x,
                 const float* __restrict__ w_ih,
                 const float* __restrict__ w_hh,
                 const float* __restrict__ b_ih,
                 const float* __restrict__ b_hh,
                 const float* __restrict__ thrp,
                 float* __restrict__ membuf,              // 2 * NB*NH floats
                 unsigned long long* __restrict__ bitmap, // NB*NS*(NH/64)
                 unsigned* __restrict__ bar,              // monotonic counters
                 float* __restrict__ out_syn,
                 float* __restrict__ out_mem)
{
    __shared__ float x_s2[2][NB * NH];            // 64 KB x_t double buffer
    __shared__ float m_s[NB * NH];                // 32 KB mem(t)
    __shared__ float sgm[16 * NB * PSTRIDE];      // 10 KB mem-partials
    __shared__ float sgx[2][16 * NB * PSTRIDE];   // 20 KB x-partials (double buf)
    __shared__ float bias_s[16];

    const int tid   = threadIdx.x;
    const int wg    = blockIdx.x;
    const int wave  = tid >> 6;       // 0..7
    const int lane  = tid & 63;
    const int g     = wave & 3;       // gate index (i,f,g,o)
    const bool ismem = (wave < 4);    // waves 0-3: w_hh / recurrence; 4-7: w_ih / projection
    const int grp   = wg >> 4;        // 16 groups x 16 WGs
    const float thr = *thrp;

    // ---- register-stationary weights: ONE matrix per wave role, 4 rows, 64 VGPRs.
    // lane k-slice: {j*256 + lane*4 .. +3 | j=0..3}
    float4 wt[4][4];
    {
        const float* WM = ismem ? w_hh : w_ih;
        #pragma unroll
        for (int rl = 0; rl < 4; ++rl) {
            const int R = g * NH + wg * HPW + rl;
            #pragma unroll
            for (int j = 0; j < 4; ++j)
                wt[rl][j] = *(const float4*)(WM + (size_t)R * ND + j * 256 + lane * 4);
        }
    }
    if (tid < 16) {
        const int R = (tid >> 2) * NH + wg * HPW + (tid & 3);
        bias_s[tid] = b_ih[R] + b_hh[R];
    }
    float c_reg = 0.f;   // cell state for pointwise threads (tid<32)

    // x-projection partial dots for slot `slot` -> sgx[slot]
    auto xdots = [&](int slot) {
        const float4* xs4 = (const float4*)x_s2[slot];
        #pragma unroll
        for (int b = 0; b < NB; ++b) {
            float4 xv[4];
            #pragma unroll
            for (int j = 0; j < 4; ++j) xv[j] = xs4[b * 256 + j * 64 + lane];
            float a0 = 0.f, a1 = 0.f, a2 = 0.f, a3 = 0.f;
            #pragma unroll
            for (int j = 0; j < 4; ++j) {
                DOT4(a0, wt[0][j], xv[j]);
                DOT4(a1, wt[1][j], xv[j]);
                DOT4(a2, wt[2][j], xv[j]);
                DOT4(a3, wt[3][j], xv[j]);
            }
            a0 += __shfl_xor(a0, 1); a0 += __shfl_xor(a0, 2);
            a1 += __shfl_xor(a1, 1); a1 += __shfl_xor(a1, 2);
            a2 += __shfl_xor(a2, 1); a2 += __shfl_xor(a2, 2);
            a3 += __shfl_xor(a3, 1); a3 += __shfl_xor(a3, 2);
            if ((lane & 3) == 0) {
                const int p = lane >> 2;
                float* dst = &sgx[slot][0];
                dst[((g * 4 + 0) * NB + b) * PSTRIDE + p] = a0;
                dst[((g * 4 + 1) * NB + b) * PSTRIDE + p] = a1;
                dst[((g * 4 + 2) * NB + b) * PSTRIDE + p] = a2;
                dst[((g * 4 + 3) * NB + b) * PSTRIDE + p] = a3;
            }
        }
    };

    // prefetch x(t1) into x_s2[slot] (fire-and-forget; drained at next __syncthreads)
    auto prefetch = [&](int slot, int t1) {
        #pragma unroll
        for (int i = 0; i < 4; ++i) {
            const int q = i * 8 + wave;          // 32 blocks of 64 chunks
            const int c0 = q * 64;               // this wave-issue covers chunks c0..c0+63
            // lane's chunk = c0 + lane; global: b = chunk>>8, d = (chunk&255)*4
            const int chunk = c0 + lane;
            const int b = chunk >> 8, d = (chunk & 255) * 4;
            __builtin_amdgcn_global_load_lds(
                (const __attribute__((address_space(1))) unsigned int*)(x + ((size_t)b * NS + t1) * ND + d),
                (__attribute__((address_space(3))) unsigned int*)&x_s2[slot][q * 256],
                16, 0, 0);
        }
    };

    // ---- prologue
    prefetch(0, 0);
    __syncthreads();
    if (!ismem) xdots(0);

    for (int t = 0; t < NS; ++t) {
        const float* mcur = membuf + (size_t)(t & 1) * (NB * NH);
        float*       mnxt = membuf + (size_t)((t + 1) & 1) * (NB * NH);

        if (t < NS - 1) prefetch((t + 1) & 1, t + 1);

        // ---- stage mem(t): all 512 threads, 4 coherent dwordx4 each
        {
            const float4* mb4 = (const float4*)mcur;
            float4 v0, v1, v2, v3;
            asm volatile(
                "global_load_dwordx4 %0, %4, off sc0 sc1\n\t"
                "global_load_dwordx4 %1, %5, off sc0 sc1\n\t"
                "global_load_dwordx4 %2, %6, off sc0 sc1\n\t"
                "global_load_dwordx4 %3, %7, off sc0 sc1\n\t"
                "s_waitcnt vmcnt(0)"
                : "=&v"(v0), "=&v"(v1), "=&v"(v2), "=&v"(v3)
                : "v"(mb4 + tid), "v"(mb4 + tid + 512),
                  "v"(mb4 + tid + 1024), "v"(mb4 + tid + 1536)
                : "memory");
            float4* ms4 = (float4*)m_s;
            ms4[tid]        = v0;
            ms4[tid + 512]  = v1;
            ms4[tid + 1024] = v2;
            ms4[tid + 1536] = v3;
        }
        __syncthreads();   // m_s ready; also drains x(t+1) prefetch into LDS

        // ---- recurrence dots (mem-waves only; x-waves wait at next barrier)
        if (ismem) {
            const float4* ms4 = (const float4*)m_s;
            #pragma unroll
            for (int b = 0; b < NB; ++b) {
                float4 mv[4];
                #pragma unroll
                for (int j = 0; j < 4; ++j) mv[j] = ms4[b * 256 + j * 64 + lane];
                float a0 = 0.f, a1 = 0.f, a2 = 0.f, a3 = 0.f;
                #pragma unroll
                for (int j = 0; j < 4; ++j) {
                    DOT4(a0, wt[0][j], mv[j]);
                    DOT4(a1, wt[1][j], mv[j]);
                    DOT4(a2, wt[2][j], mv[j]);
                    DOT4(a3, wt[3][j], mv[j]);
                }
                a0 += __shfl_xor(a0, 1); a0 += __shfl_xor(a0, 2);
                a1 += __shfl_xor(a1, 1); a1 += __shfl_xor(a1, 2);
                a2 += __shfl_xor(a2, 1); a2 += __shfl_xor(a2, 2);
                a3 += __shfl_xor(a3, 1); a3 += __shfl_xor(a3, 2);
                if ((lane & 3) == 0) {
                    const int p = lane >> 2;
                    sgm[((g * 4 + 0) * NB + b) * PSTRIDE + p] = a0;
                    sgm[((g * 4 + 1) * NB + b) * PSTRIDE + p] = a1;
                    sgm[((g * 4 + 2) * NB + b) * PSTRIDE + p] = a2;
                    sgm[((g * 4 + 3) * NB + b) * PSTRIDE + p] = a3;
                }
            }
        }
        __syncthreads();   // sgm ready (sgx[t&1] was ready one step ago)

        // ---- pointwise LSTM update: 32 threads of wave 0
        if (tid < 32) {
            const int hl = tid >> 3, b = tid & 7;
            const int h  = wg * HPW + hl;
            float gv[4];
            #pragma unroll
            for (int gg = 0; gg < 4; ++gg) {
                const int r = gg * 4 + hl;
                const float4* pm = (const float4*)&sgm[(r * NB + b) * PSTRIDE];
                const float4* px = (const float4*)&sgx[t & 1][(r * NB + b) * PSTRIDE];
                float s = bias_s[r];
                #pragma unroll
                for (int q = 0; q < 4; ++q) {
                    float4 vm = pm[q], vx = px[q];
                    s += vm.x + vm.y + vm.z + vm.w + vx.x + vx.y + vx.z + vx.w;
                }
                gv[gg] = s;
            }
            const float cn = sigmf(gv[1]) * c_reg + sigmf(gv[0]) * tanh_fast(gv[2]);
            const float hv = sigmf(gv[3]) * tanh_fast(cn);
            const float mprev = m_s[b * NH + h];
            const float reset = (mprev - thr > 0.f) ? 1.f : 0.f;  // snntorch: prev-mem reset
            const float mn = hv - reset * thr;
            c_reg = cn;
            __hip_atomic_store((unsigned*)(mnxt + b * NH + h), __float_as_uint(mn),
                               __ATOMIC_RELAXED, SCOPE_AGENT);
            if (mn - thr > 0.f)
                atomicOr(bitmap + (size_t)(b * NS + t) * (NH / 64) + (h >> 6),
                         1ull << (h & 63));
            if (t == NS - 1) {
                out_syn[b * NH + h] = cn;
                out_mem[b * NH + h] = mn;
            }
        }

        if (t < NS - 1) {
            // arrive (release RMW drains wave 0's mem stores first)
            if (tid == 0) {
                unsigned prev = __hip_atomic_fetch_add(bar + grp * 32, 1u,
                                                       __ATOMIC_ACQ_REL, SCOPE_AGENT);
                if ((prev & 15u) == 15u) {
                    unsigned p2 = __hip_atomic_fetch_add(bar + 512, 1u,
                                                         __ATOMIC_ACQ_REL, SCOPE_AGENT);
                    if ((p2 & 15u) == 15u)
                        __hip_atomic_store(bar + 544, (unsigned)(t + 1),
                                           __ATOMIC_RELEASE, SCOPE_AGENT);
                }
            }

            // x-projection for t+1 runs in the barrier shadow (waves 4-7)
            if (!ismem) xdots((t + 1) & 1);

            if (tid == 0) {
                const unsigned want = (unsigned)(t + 1);
                while (__hip_atomic_load(bar + 544, __ATOMIC_RELAXED, SCOPE_AGENT) < want)
                    __builtin_amdgcn_s_sleep(1);
            }
            asm volatile("" ::: "memory");
            __syncthreads();
        }
    }
}

// out[b,s,:] = dyt_w * tanh(alpha * (x + b_fc + spk @ w_fc^T)) + dyt_b
__global__ __launch_bounds__(256)
void out_kernel(const float* __restrict__ x,
                const float* __restrict__ b_fc,
                const float* __restrict__ w_fc,
                const float* __restrict__ alphap,
                const float* __restrict__ dytw,
                const float* __restrict__ dytb,
                const unsigned long long* __restrict__ bitmap,
                float* __restrict__ out)
{
    __shared__ unsigned long long wds[16];
    __shared__ int flag;
    const int row = blockIdx.x;      // b*NS + s
    const int tid = threadIdx.x;
    if (tid < 16) wds[tid] = bitmap[(size_t)row * 16 + tid];
    __syncthreads();
    if (tid == 0) {
        unsigned long long o = 0ull;
        #pragma unroll
        for (int i = 0; i < 16; ++i) o |= wds[i];
        flag = (o != 0ull);
    }
    __syncthreads();

    const float alpha = *alphap;
    const float* xr = x + (size_t)row * NH;
    float* orow = out + (size_t)row * NH;
    const int j0 = tid * 4;

    float4 xv = *(const float4*)(xr + j0);
    float4 bf = *(const float4*)(b_fc + j0);
    float4 dw = *(const float4*)(dytw + j0);
    float4 db = *(const float4*)(dytb + j0);
    float p[4]   = {xv.x, xv.y, xv.z, xv.w};
    float bfa[4] = {bf.x, bf.y, bf.z, bf.w};
    float dwa[4] = {dw.x, dw.y, dw.z, dw.w};
    float dba[4] = {db.x, db.y, db.z, db.w};

    #pragma unroll
    for (int u = 0; u < 4; ++u) {
        float v = p[u] + bfa[u];
        if (flag) {   // general spike path (cold on this data)
            const int j = j0 + u;
            for (int wi = 0; wi < 16; ++wi) {
                unsigned long long m = wds[wi];
                while (m) {
                    int bit = __ffsll(m) - 1;
                    m &= m - 1;
                    v += w_fc[(size_t)j * NH + wi * 64 + bit];
                }
            }
        }
        p[u] = dwa[u] * tanh_fast(alpha * v) + dba[u];
    }
    *(float4*)(orow + j0) = make_float4(p[0], p[1], p[2], p[3]);
}

extern "C" void kernel_launch(void* const* d_in, const int* in_sizes, int n_in,
                              void* d_out, int out_size, void* d_ws, size_t ws_size,
                              hipStream_t stream) {
    const float* x     = (const float*)d_in[0];
    const float* w_ih  = (const float*)d_in[1];
    const float* w_hh  = (const float*)d_in[2];
    const float* b_ih  = (const float*)d_in[3];
    const float* b_hh  = (const float*)d_in[4];
    const float* w_fc  = (const float*)d_in[5];
    const float* b_fc  = (const float*)d_in[6];
    const float* thr   = (const float*)d_in[7];
    const float* alpha = (const float*)d_in[8];
    const float* dytw  = (const float*)d_in[9];
    const float* dytb  = (const float*)d_in[10];

    float* out  = (float*)d_out;
    float* syn  = out + (size_t)NB * NS * NH;
    float* memf = syn + (size_t)NB * NH;

    char* ws = (char*)d_ws;
    unsigned* bar   = (unsigned*)ws;                                  // 4 KB barrier region
    float* membuf   = (float*)(ws + 4096);                            // 64 KB double buffer
    unsigned long long* bitmap = (unsigned long long*)(ws + 4096 + 2 * NB * NH * 4);

    size_t zbytes = 4096 + (size_t)2 * NB * NH * 4
                  + (size_t)NB * NS * (NH / 64) * 8;                  // ~2.17 MB
    (void)hipMemsetAsync(d_ws, 0, zbytes, stream);

    hipLaunchKernelGGL(scan_kernel, dim3(NWG), dim3(TPB), 0, stream,
                       x, w_ih, w_hh, b_ih, b_hh, thr, membuf, bitmap, bar, syn, memf);
    hipLaunchKernelGGL(out_kernel, dim3(NB * NS), dim3(256), 0, stream,
                       x, b_fc, w_fc, alpha, dytw, dytb, bitmap, out);
}

// Round 6
// 12958.325 us; speedup vs baseline: 5.2301x; 1.7479x over previous
//
#include <hip/hip_runtime.h>

#define NB 8
#define NS 2048
#define ND 1024
#define NH 1024
#define NWG 256
#define TPB 512
#define HPW 4        /* h-coords per WG = NH / NWG */
#define PSTRIDE 20   /* padded stride (floats) for 16 partials */

#define SCOPE_AGENT __HIP_MEMORY_SCOPE_AGENT

__device__ __forceinline__ float sigmf(float v)     { return 1.f / (1.f + __expf(-v)); }
__device__ __forceinline__ float tanh_fast(float v) { return 1.f - 2.f / (1.f + __expf(2.f * v)); }

#define DOT4(acc, W, V)                 \
    acc = fmaf((W).x, (V).x, acc);      \
    acc = fmaf((W).y, (V).y, acc);      \
    acc = fmaf((W).z, (V).z, acc);      \
    acc = fmaf((W).w, (V).w, acc);

__global__ __launch_bounds__(TPB, 2)
void scan_kernel(const float* __restrict__ x,
                 const float* __restrict__ w_ih,
                 const float* __restrict__ w_hh,
                 const float* __restrict__ b_ih,
                 const float* __restrict__ b_hh,
                 const float* __restrict__ thrp,
                 unsigned long long* __restrict__ membuf,  // 2 * NB*NH tagged pairs
                 unsigned long long* __restrict__ bitmap,  // NB*NS*(NH/64)
                 float* __restrict__ out_syn,
                 float* __restrict__ out_mem)
{
    __shared__ float x_s2[2][NB * NH];            // 64 KB x_t double buffer
    __shared__ float m_s[NB * NH];                // 32 KB mem(t) values
    __shared__ float sgm[16 * NB * PSTRIDE];      // mem-partials
    __shared__ float sgx[2][16 * NB * PSTRIDE];   // x-partials (double buf)
    __shared__ float bias_s[16];

    const int tid   = threadIdx.x;
    const int wg    = blockIdx.x;
    const int wave  = tid >> 6;       // 0..7
    const int lane  = tid & 63;
    const int g     = wave & 3;       // gate index (i,f,g,o)
    const bool ismem = (wave < 4);    // waves 0-3: w_hh; waves 4-7: w_ih
    const float thr = *thrp;

    // ---- register-stationary weights: ONE matrix per wave role, 4 rows = 64 VGPRs
    float4 wt[4][4];
    {
        const float* WM = ismem ? w_hh : w_ih;
        #pragma unroll
        for (int rl = 0; rl < 4; ++rl) {
            const int R = g * NH + wg * HPW + rl;
            #pragma unroll
            for (int j = 0; j < 4; ++j)
                wt[rl][j] = *(const float4*)(WM + (size_t)R * ND + j * 256 + lane * 4);
        }
    }
    if (tid < 16) {
        const int R = (tid >> 2) * NH + wg * HPW + (tid & 3);
        bias_s[tid] = b_ih[R] + b_hh[R];
    }
    float c_reg = 0.f;   // cell state (pointwise threads, tid<32)

    auto xdots = [&](int slot) {
        const float4* xs4 = (const float4*)x_s2[slot];
        #pragma unroll
        for (int b = 0; b < NB; ++b) {
            float4 xv[4];
            #pragma unroll
            for (int j = 0; j < 4; ++j) xv[j] = xs4[b * 256 + j * 64 + lane];
            float a0 = 0.f, a1 = 0.f, a2 = 0.f, a3 = 0.f;
            #pragma unroll
            for (int j = 0; j < 4; ++j) {
                DOT4(a0, wt[0][j], xv[j]);
                DOT4(a1, wt[1][j], xv[j]);
                DOT4(a2, wt[2][j], xv[j]);
                DOT4(a3, wt[3][j], xv[j]);
            }
            a0 += __shfl_xor(a0, 1); a0 += __shfl_xor(a0, 2);
            a1 += __shfl_xor(a1, 1); a1 += __shfl_xor(a1, 2);
            a2 += __shfl_xor(a2, 1); a2 += __shfl_xor(a2, 2);
            a3 += __shfl_xor(a3, 1); a3 += __shfl_xor(a3, 2);
            if ((lane & 3) == 0) {
                const int p = lane >> 2;
                float* dst = &sgx[slot][0];
                dst[((g * 4 + 0) * NB + b) * PSTRIDE + p] = a0;
                dst[((g * 4 + 1) * NB + b) * PSTRIDE + p] = a1;
                dst[((g * 4 + 2) * NB + b) * PSTRIDE + p] = a2;
                dst[((g * 4 + 3) * NB + b) * PSTRIDE + p] = a3;
            }
        }
    };

    auto prefetch = [&](int slot, int t1) {
        #pragma unroll
        for (int i = 0; i < 4; ++i) {
            const int q = i * 8 + wave;
            const int chunk = q * 64 + lane;
            const int b = chunk >> 8, d = (chunk & 255) * 4;
            __builtin_amdgcn_global_load_lds(
                (const __attribute__((address_space(1))) unsigned int*)(x + ((size_t)b * NS + t1) * ND + d),
                (__attribute__((address_space(3))) unsigned int*)&x_s2[slot][q * 256],
                16, 0, 0);
        }
    };

    // ---- prologue
    prefetch(0, 0);
    __syncthreads();
    if (!ismem) xdots(0);

    for (int t = 0; t < NS; ++t) {
        const unsigned long long* mc = membuf + (size_t)(t & 1) * (NB * NH);
        unsigned long long*       mn64 = membuf + (size_t)((t + 1) & 1) * (NB * NH);

        if (t < NS - 1) prefetch((t + 1) & 1, t + 1);

        // ---- stage mem(t): tagged-pair polling, no barrier.
        {
            const unsigned want = (unsigned)t;
            unsigned long long warr[16];
            #pragma unroll
            for (int k = 0; k < 16; ++k)
                warr[k] = __hip_atomic_load(mc + tid + k * TPB,
                                            __ATOMIC_RELAXED, SCOPE_AGENT);
            unsigned pend = 0;
            #pragma unroll
            for (int k = 0; k < 16; ++k) {
                if ((unsigned)(warr[k] >> 32) == want)
                    m_s[tid + k * TPB] = __uint_as_float((unsigned)warr[k]);
                else
                    pend |= (1u << k);
            }
            while (pend) {                  // vectorized retry for stragglers
                unsigned long long w2[16];
                unsigned np = 0;
                #pragma unroll
                for (int k = 0; k < 16; ++k)
                    if (pend & (1u << k))
                        w2[k] = __hip_atomic_load(mc + tid + k * TPB,
                                                  __ATOMIC_RELAXED, SCOPE_AGENT);
                #pragma unroll
                for (int k = 0; k < 16; ++k)
                    if (pend & (1u << k)) {
                        if ((unsigned)(w2[k] >> 32) == want)
                            m_s[tid + k * TPB] = __uint_as_float((unsigned)w2[k]);
                        else
                            np |= (1u << k);
                    }
                pend = np;
            }
        }
        __syncthreads();   // m_s ready; x(t+1) prefetch drained too

        // ---- recurrence dots (mem-waves)
        if (ismem) {
            const float4* ms4 = (const float4*)m_s;
            #pragma unroll
            for (int b = 0; b < NB; ++b) {
                float4 mv[4];
                #pragma unroll
                for (int j = 0; j < 4; ++j) mv[j] = ms4[b * 256 + j * 64 + lane];
                float a0 = 0.f, a1 = 0.f, a2 = 0.f, a3 = 0.f;
                #pragma unroll
                for (int j = 0; j < 4; ++j) {
                    DOT4(a0, wt[0][j], mv[j]);
                    DOT4(a1, wt[1][j], mv[j]);
                    DOT4(a2, wt[2][j], mv[j]);
                    DOT4(a3, wt[3][j], mv[j]);
                }
                a0 += __shfl_xor(a0, 1); a0 += __shfl_xor(a0, 2);
                a1 += __shfl_xor(a1, 1); a1 += __shfl_xor(a1, 2);
                a2 += __shfl_xor(a2, 1); a2 += __shfl_xor(a2, 2);
                a3 += __shfl_xor(a3, 1); a3 += __shfl_xor(a3, 2);
                if ((lane & 3) == 0) {
                    const int p = lane >> 2;
                    sgm[((g * 4 + 0) * NB + b) * PSTRIDE + p] = a0;
                    sgm[((g * 4 + 1) * NB + b) * PSTRIDE + p] = a1;
                    sgm[((g * 4 + 2) * NB + b) * PSTRIDE + p] = a2;
                    sgm[((g * 4 + 3) * NB + b) * PSTRIDE + p] = a3;
                }
            }
        } else if (t < NS - 1) {
            // x-projection for t+1 (parallel with mem-dots, off critical path)
            xdots((t + 1) & 1);
        }
        __syncthreads();   // sgm ready (sgx[t&1] ready since last step)

        // ---- pointwise LSTM update + tagged publish: 32 threads of wave 0
        if (tid < 32) {
            const int hl = tid >> 3, b = tid & 7;
            const int h  = wg * HPW + hl;
            float gv[4];
            #pragma unroll
            for (int gg = 0; gg < 4; ++gg) {
                const int r = gg * 4 + hl;
                const float4* pm = (const float4*)&sgm[(r * NB + b) * PSTRIDE];
                const float4* px = (const float4*)&sgx[t & 1][(r * NB + b) * PSTRIDE];
                float s = bias_s[r];
                #pragma unroll
                for (int q = 0; q < 4; ++q) {
                    float4 vm = pm[q], vx = px[q];
                    s += vm.x + vm.y + vm.z + vm.w + vx.x + vx.y + vx.z + vx.w;
                }
                gv[gg] = s;
            }
            const float cn = sigmf(gv[1]) * c_reg + sigmf(gv[0]) * tanh_fast(gv[2]);
            const float hv = sigmf(gv[3]) * tanh_fast(cn);
            const float mprev = m_s[b * NH + h];
            const float reset = (mprev - thr > 0.f) ? 1.f : 0.f;  // snntorch: prev-mem reset
            const float mn = hv - reset * thr;
            c_reg = cn;
            const unsigned long long pk =
                ((unsigned long long)(unsigned)(t + 1) << 32) | __float_as_uint(mn);
            __hip_atomic_store(mn64 + b * NH + h, pk, __ATOMIC_RELAXED, SCOPE_AGENT);
            if (mn - thr > 0.f)
                atomicOr(bitmap + (size_t)(b * NS + t) * (NH / 64) + (h >> 6),
                         1ull << (h & 63));
            if (t == NS - 1) {
                out_syn[b * NH + h] = cn;
                out_mem[b * NH + h] = mn;
            }
        }
        __syncthreads();   // protect m_s/sgm from next step's overwrite
    }
}

// out[b,s,:] = dyt_w * tanh(alpha * (x + b_fc + spk @ w_fc^T)) + dyt_b
__global__ __launch_bounds__(256)
void out_kernel(const float* __restrict__ x,
                const float* __restrict__ b_fc,
                const float* __restrict__ w_fc,
                const float* __restrict__ alphap,
                const float* __restrict__ dytw,
                const float* __restrict__ dytb,
                const unsigned long long* __restrict__ bitmap,
                float* __restrict__ out)
{
    __shared__ unsigned long long wds[16];
    __shared__ int flag;
    const int row = blockIdx.x;      // b*NS + s
    const int tid = threadIdx.x;
    if (tid < 16) wds[tid] = bitmap[(size_t)row * 16 + tid];
    __syncthreads();
    if (tid == 0) {
        unsigned long long o = 0ull;
        #pragma unroll
        for (int i = 0; i < 16; ++i) o |= wds[i];
        flag = (o != 0ull);
    }
    __syncthreads();

    const float alpha = *alphap;
    const float* xr = x + (size_t)row * NH;
    float* orow = out + (size_t)row * NH;
    const int j0 = tid * 4;

    float4 xv = *(const float4*)(xr + j0);
    float4 bf = *(const float4*)(b_fc + j0);
    float4 dw = *(const float4*)(dytw + j0);
    float4 db = *(const float4*)(dytb + j0);
    float p[4]   = {xv.x, xv.y, xv.z, xv.w};
    float bfa[4] = {bf.x, bf.y, bf.z, bf.w};
    float dwa[4] = {dw.x, dw.y, dw.z, dw.w};
    float dba[4] = {db.x, db.y, db.z, db.w};

    #pragma unroll
    for (int u = 0; u < 4; ++u) {
        float v = p[u] + bfa[u];
        if (flag) {   // general spike path (cold on this data)
            const int j = j0 + u;
            for (int wi = 0; wi < 16; ++wi) {
                unsigned long long m = wds[wi];
                while (m) {
                    int bit = __ffsll(m) - 1;
                    m &= m - 1;
                    v += w_fc[(size_t)j * NH + wi * 64 + bit];
                }
            }
        }
        p[u] = dwa[u] * tanh_fast(alpha * v) + dba[u];
    }
    *(float4*)(orow + j0) = make_float4(p[0], p[1], p[2], p[3]);
}

extern "C" void kernel_launch(void* const* d_in, const int* in_sizes, int n_in,
                              void* d_out, int out_size, void* d_ws, size_t ws_size,
                              hipStream_t stream) {
    const float* x     = (const float*)d_in[0];
    const float* w_ih  = (const float*)d_in[1];
    const float* w_hh  = (const float*)d_in[2];
    const float* b_ih  = (const float*)d_in[3];
    const float* b_hh  = (const float*)d_in[4];
    const float* w_fc  = (const float*)d_in[5];
    const float* b_fc  = (const float*)d_in[6];
    const float* thr   = (const float*)d_in[7];
    const float* alpha = (const float*)d_in[8];
    const float* dytw  = (const float*)d_in[9];
    const float* dytb  = (const float*)d_in[10];

    float* out  = (float*)d_out;
    float* syn  = out + (size_t)NB * NS * NH;
    float* memf = syn + (size_t)NB * NH;

    char* ws = (char*)d_ws;
    unsigned long long* membuf = (unsigned long long*)ws;             // 128 KB tagged pairs
    unsigned long long* bitmap = (unsigned long long*)(ws + 131072);

    size_t zbytes = 131072 + (size_t)NB * NS * (NH / 64) * 8;         // ~2.2 MB
    (void)hipMemsetAsync(d_ws, 0, zbytes, stream);

    hipLaunchKernelGGL(scan_kernel, dim3(NWG), dim3(TPB), 0, stream,
                       x, w_ih, w_hh, b_ih, b_hh, thr, membuf, bitmap, syn, memf);
    hipLaunchKernelGGL(out_kernel, dim3(NB * NS), dim3(256), 0, stream,
                       x, b_fc, w_fc, alpha, dytw, dytb, bitmap, out);
}

// Round 8
// 11263.802 us; speedup vs baseline: 6.0169x; 1.1504x over previous
//
#include <hip/hip_runtime.h>

#define NB 8
#define NS 2048
#define ND 1024
#define NH 1024
#define NWG 256
#define TPB 1024
#define NBG 4        /* batches per group */
#define HPW 8        /* h-coords per WG = NH / 128 */
#define PSTRIDE 20   /* padded stride (floats) for 16 partials */

#define SCOPE_AGENT __HIP_MEMORY_SCOPE_AGENT

__device__ __forceinline__ float sigmf(float v)     { return 1.f / (1.f + __expf(-v)); }
__device__ __forceinline__ float tanh_fast(float v) { return 1.f - 2.f / (1.f + __expf(2.f * v)); }

#define DOT4(acc, W, V)                 \
    acc = fmaf((W).x, (V).x, acc);      \
    acc = fmaf((W).y, (V).y, acc);      \
    acc = fmaf((W).z, (V).z, acc);      \
    acc = fmaf((W).w, (V).w, acc);

__device__ __forceinline__ float bf16_unpack(unsigned w) {
    return __uint_as_float((w & 0xFFFFu) << 16);
}
__device__ __forceinline__ unsigned bf16_rne(float f) {
    unsigned b = __float_as_uint(f);
    return (b + 0x7FFFu + ((b >> 16) & 1u)) >> 16;
}

__global__ __launch_bounds__(TPB, 4)
void scan_kernel(const float* __restrict__ x,
                 const float* __restrict__ w_ih,
                 const float* __restrict__ w_hh,
                 const float* __restrict__ b_ih,
                 const float* __restrict__ b_hh,
                 const float* __restrict__ thrp,
                 unsigned* __restrict__ membuf,            // [2][8][1024] tag16|bf16 words
                 unsigned long long* __restrict__ bitmap,  // NB*NS*(NH/64)
                 float* __restrict__ out_syn,
                 float* __restrict__ out_mem)
{
    __shared__ float x_s2[2][NBG * NH];          // 32 KB x_t double buffer (group's 4 batches)
    __shared__ float m_s[NBG * NH];              // 16 KB mem(t) values (4 batches)
    __shared__ float sgm[32 * NBG * PSTRIDE];    // 10 KB mem-partials (32 rows x 4 b x 16)
    __shared__ float sgx[2][32 * NBG * PSTRIDE]; // 20 KB x-partials (double buf)
    __shared__ float bias_s[32];

    const int tid   = threadIdx.x;
    const int wg    = blockIdx.x;
    const int grpb  = wg >> 7;          // batch group: 0 -> b0..3, 1 -> b4..7
    const int wgl   = wg & 127;
    const int hb    = wgl * HPW;        // 8 h-coords per WG
    const int wave  = tid >> 6;         // 0..15
    const int lane  = tid & 63;
    const bool ismem = (wave < 8);      // waves 0-7: w_hh; 8-15: w_ih
    const int wx    = wave & 7;
    const int g     = wx & 3;           // gate (i,f,g,o)
    const int hh0   = (wx >> 2) * 4;    // h-subblock: 0 or 4
    const float thr = *thrp;

    // ---- register-stationary weights: 4 rows x 16 floats = 64 VGPRs per wave
    float4 wt[4][4];
    {
        const float* WM = ismem ? w_hh : w_ih;
        #pragma unroll
        for (int rl = 0; rl < 4; ++rl) {
            const int R = g * NH + hb + hh0 + rl;
            #pragma unroll
            for (int j = 0; j < 4; ++j)
                wt[rl][j] = *(const float4*)(WM + (size_t)R * ND + j * 256 + lane * 4);
        }
    }
    if (tid < 32) {
        const int R = (tid >> 3) * NH + hb + (tid & 7);
        bias_s[tid] = b_ih[R] + b_hh[R];
    }
    float c_reg = 0.f;   // cell state (pointwise threads tid<32)

    // x-projection partials into sgx[slot] (x-waves)
    auto xdots = [&](int slot) {
        const float4* xs4 = (const float4*)x_s2[slot];
        #pragma unroll
        for (int bl = 0; bl < NBG; ++bl) {
            float4 xv[4];
            #pragma unroll
            for (int j = 0; j < 4; ++j) xv[j] = xs4[bl * 256 + j * 64 + lane];
            float a0 = 0.f, a1 = 0.f, a2 = 0.f, a3 = 0.f;
            #pragma unroll
            for (int j = 0; j < 4; ++j) {
                DOT4(a0, wt[0][j], xv[j]);
                DOT4(a1, wt[1][j], xv[j]);
                DOT4(a2, wt[2][j], xv[j]);
                DOT4(a3, wt[3][j], xv[j]);
            }
            a0 += __shfl_xor(a0, 1); a0 += __shfl_xor(a0, 2);
            a1 += __shfl_xor(a1, 1); a1 += __shfl_xor(a1, 2);
            a2 += __shfl_xor(a2, 1); a2 += __shfl_xor(a2, 2);
            a3 += __shfl_xor(a3, 1); a3 += __shfl_xor(a3, 2);
            if ((lane & 3) == 0) {
                const int p = lane >> 2;
                float* dst = &sgx[slot][0];
                const int r0 = g * 8 + hh0;
                dst[((r0 + 0) * NBG + bl) * PSTRIDE + p] = a0;
                dst[((r0 + 1) * NBG + bl) * PSTRIDE + p] = a1;
                dst[((r0 + 2) * NBG + bl) * PSTRIDE + p] = a2;
                dst[((r0 + 3) * NBG + bl) * PSTRIDE + p] = a3;
            }
        }
    };

    // prefetch x(t1) for this group's 4 batches -> x_s2[slot]
    auto prefetch = [&](int slot, int t1) {
        const int bl = tid >> 8, d = (tid & 255) * 4;
        __builtin_amdgcn_global_load_lds(
            (const __attribute__((address_space(1))) unsigned int*)
                (x + ((size_t)(grpb * NBG + bl) * NS + t1) * ND + d),
            (__attribute__((address_space(3))) unsigned int*)&x_s2[slot][tid * 4],
            16, 0, 0);
    };

    // ---- prologue
    prefetch(0, 0);
    __syncthreads();
    if (!ismem) xdots(0);

    for (int t = 0; t < NS; ++t) {
        const int cs = t & 1, ns_ = (t + 1) & 1;
        const unsigned* mc = membuf + (size_t)(cs * 8 + grpb * NBG) * NH;
        unsigned*       mp = membuf + (size_t)(ns_ * 8 + grpb * NBG) * NH;

        if (t < NS - 1) prefetch(ns_, t + 1);

        // ---- stage mem(t): one coherent dwordx4 of tag16|bf16 words per thread
        {
            const unsigned want = (unsigned)t;
            uint4 v;
            asm volatile(
                "global_load_dwordx4 %0, %1, off sc0 sc1\n\t"
                "s_waitcnt vmcnt(0)"
                : "=&v"(v) : "v"(mc + tid * 4) : "memory");
            unsigned w0 = v.x, w1 = v.y, w2 = v.z, w3 = v.w;
            #pragma unroll
            for (int k = 0; k < 4; ++k) {
                unsigned w = (k == 0) ? w0 : (k == 1) ? w1 : (k == 2) ? w2 : w3;
                while ((w >> 16) != want) {
                    __builtin_amdgcn_s_sleep(1);
                    w = __hip_atomic_load(mc + tid * 4 + k, __ATOMIC_RELAXED, SCOPE_AGENT);
                }
                m_s[tid * 4 + k] = bf16_unpack(w);
            }
        }
        __syncthreads();   // m_s ready; x(t+1) prefetch drained too

        // ---- recurrence dots (mem-waves) || x-projection for t+1 (x-waves)
        if (ismem) {
            const float4* ms4 = (const float4*)m_s;
            #pragma unroll
            for (int bl = 0; bl < NBG; ++bl) {
                float4 mv[4];
                #pragma unroll
                for (int j = 0; j < 4; ++j) mv[j] = ms4[bl * 256 + j * 64 + lane];
                float a0 = 0.f, a1 = 0.f, a2 = 0.f, a3 = 0.f;
                #pragma unroll
                for (int j = 0; j < 4; ++j) {
                    DOT4(a0, wt[0][j], mv[j]);
                    DOT4(a1, wt[1][j], mv[j]);
                    DOT4(a2, wt[2][j], mv[j]);
                    DOT4(a3, wt[3][j], mv[j]);
                }
                a0 += __shfl_xor(a0, 1); a0 += __shfl_xor(a0, 2);
                a1 += __shfl_xor(a1, 1); a1 += __shfl_xor(a1, 2);
                a2 += __shfl_xor(a2, 1); a2 += __shfl_xor(a2, 2);
                a3 += __shfl_xor(a3, 1); a3 += __shfl_xor(a3, 2);
                if ((lane & 3) == 0) {
                    const int p = lane >> 2;
                    const int r0 = g * 8 + hh0;
                    sgm[((r0 + 0) * NBG + bl) * PSTRIDE + p] = a0;
                    sgm[((r0 + 1) * NBG + bl) * PSTRIDE + p] = a1;
                    sgm[((r0 + 2) * NBG + bl) * PSTRIDE + p] = a2;
                    sgm[((r0 + 3) * NBG + bl) * PSTRIDE + p] = a3;
                }
            }
        } else if (t < NS - 1) {
            xdots(ns_);
        }
        __syncthreads();   // sgm ready (sgx[t&1] ready since last step)

        // ---- pointwise LSTM update + tagged publish: 32 threads (8 h x 4 b)
        if (tid < 32) {
            const int hl = tid >> 2, bl = tid & 3;
            const int h  = hb + hl;
            const int bg = grpb * NBG + bl;
            float gv[4];
            #pragma unroll
            for (int gg = 0; gg < 4; ++gg) {
                const int r = gg * 8 + hl;
                const float4* pm = (const float4*)&sgm[(r * NBG + bl) * PSTRIDE];
                const float4* px = (const float4*)&sgx[cs][(r * NBG + bl) * PSTRIDE];
                float s = bias_s[r];
                #pragma unroll
                for (int q = 0; q < 4; ++q) {
                    float4 vm = pm[q], vx = px[q];
                    s += vm.x + vm.y + vm.z + vm.w + vx.x + vx.y + vx.z + vx.w;
                }
                gv[gg] = s;
            }
            const float cn = sigmf(gv[1]) * c_reg + sigmf(gv[0]) * tanh_fast(gv[2]);
            const float hv = sigmf(gv[3]) * tanh_fast(cn);
            const float mprev = m_s[bl * NH + h];
            const float reset = (mprev - thr > 0.f) ? 1.f : 0.f;  // snntorch: prev-mem reset
            const float mn = hv - reset * thr;
            c_reg = cn;
            const unsigned pk = ((unsigned)(t + 1) << 16) | bf16_rne(mn);
            __hip_atomic_store(mp + bl * NH + h, pk, __ATOMIC_RELAXED, SCOPE_AGENT);
            if (mn - thr > 0.f)
                atomicOr(bitmap + (size_t)(bg * NS + t) * (NH / 64) + (h >> 6),
                         1ull << (h & 63));
            if (t == NS - 1) {
                out_syn[bg * NH + h] = cn;
                out_mem[bg * NH + h] = mn;
            }
        }
        __syncthreads();   // protect m_s/sgm/sgx from next step's overwrite
    }
}

// out[b,s,:] = dyt_w * tanh(alpha * (x + b_fc + spk @ w_fc^T)) + dyt_b
__global__ __launch_bounds__(256)
void out_kernel(const float* __restrict__ x,
                const float* __restrict__ b_fc,
                const float* __restrict__ w_fc,
                const float* __restrict__ alphap,
                const float* __restrict__ dytw,
                const float* __restrict__ dytb,
                const unsigned long long* __restrict__ bitmap,
                float* __restrict__ out)
{
    __shared__ unsigned long long wds[16];
    __shared__ int flag;
    const int row = blockIdx.x;      // b*NS + s
    const int tid = threadIdx.x;
    if (tid < 16) wds[tid] = bitmap[(size_t)row * 16 + tid];
    __syncthreads();
    if (tid == 0) {
        unsigned long long o = 0ull;
        #pragma unroll
        for (int i = 0; i < 16; ++i) o |= wds[i];
        flag = (o != 0ull);
    }
    __syncthreads();

    const float alpha = *alphap;
    const float* xr = x + (size_t)row * NH;
    float* orow = out + (size_t)row * NH;
    const int j0 = tid * 4;

    float4 xv = *(const float4*)(xr + j0);
    float4 bf = *(const float4*)(b_fc + j0);
    float4 dw = *(const float4*)(dytw + j0);
    float4 db = *(const float4*)(dytb + j0);
    float p[4]   = {xv.x, xv.y, xv.z, xv.w};
    float bfa[4] = {bf.x, bf.y, bf.z, bf.w};
    float dwa[4] = {dw.x, dw.y, dw.z, dw.w};
    float dba[4] = {db.x, db.y, db.z, db.w};

    #pragma unroll
    for (int u = 0; u < 4; ++u) {
        float v = p[u] + bfa[u];
        if (flag) {   // general spike path (cold on this data)
            const int j = j0 + u;
            for (int wi = 0; wi < 16; ++wi) {
                unsigned long long m = wds[wi];
                while (m) {
                    int bit = __ffsll(m) - 1;
                    m &= m - 1;
                    v += w_fc[(size_t)j * NH + wi * 64 + bit];
                }
            }
        }
        p[u] = dwa[u] * tanh_fast(alpha * v) + dba[u];
    }
    *(float4*)(orow + j0) = make_float4(p[0], p[1], p[2], p[3]);
}

extern "C" void kernel_launch(void* const* d_in, const int* in_sizes, int n_in,
                              void* d_out, int out_size, void* d_ws, size_t ws_size,
                              hipStream_t stream) {
    const float* x     = (const float*)d_in[0];
    const float* w_ih  = (const float*)d_in[1];
    const float* w_hh  = (const float*)d_in[2];
    const float* b_ih  = (const float*)d_in[3];
    const float* b_hh  = (const float*)d_in[4];
    const float* w_fc  = (const float*)d_in[5];
    const float* b_fc  = (const float*)d_in[6];
    const float* thr   = (const float*)d_in[7];
    const float* alpha = (const float*)d_in[8];
    const float* dytw  = (const float*)d_in[9];
    const float* dytb  = (const float*)d_in[10];

    float* out  = (float*)d_out;
    float* syn  = out + (size_t)NB * NS * NH;
    float* memf = syn + (size_t)NB * NH;

    char* ws = (char*)d_ws;
    unsigned* membuf = (unsigned*)ws;                                 // 64 KB tagged words
    unsigned long long* bitmap = (unsigned long long*)(ws + 65536);

    size_t zbytes = 65536 + (size_t)NB * NS * (NH / 64) * 8;          // ~2.1 MB
    (void)hipMemsetAsync(d_ws, 0, zbytes, stream);

    hipLaunchKernelGGL(scan_kernel, dim3(NWG), dim3(TPB), 0, stream,
                       x, w_ih, w_hh, b_ih, b_hh, thr, membuf, bitmap, syn, memf);
    hipLaunchKernelGGL(out_kernel, dim3(NB * NS), dim3(256), 0, stream,
                       x, b_fc, w_fc, alpha, dytw, dytb, bitmap, out);
}